// Round 1
// baseline (323.043 us; speedup 1.0000x reference)
//
#include <hip/hip_runtime.h>

#define EPSF 1e-10f

constexpr int B = 32, K = 4, M = 3;
constexpr int NPIX = 256 * 256;
constexpr int BLOCKS_PER_B = 64;   // 64 blocks x 256 thr x 4 px = 65536 px per b
constexpr int THREADS = 256;

// workspace float layout
constexpr int OFF_N     = 0;                  // [B]     sum(mask)
constexpr int OFF_W     = OFF_N + B;          // [B*K]   sum(mask*pred)
constexpr int OFF_P     = OFF_W + B * K;      // [B*K*M] sum(mask*pred*x)
constexpr int OFF_Q     = OFF_P + B * K * M;  // [B*K*M] sum(mask*pred*x^2)
constexpr int OFF_ALPHA = OFF_Q + B * K * M;  // [B*K]
constexpr int OFF_MU    = OFF_ALPHA + B * K;  // [B*K*M]
constexpr int OFF_IV    = OFF_MU + B * K * M; // [B*K*M] 1/(2*var)
constexpr int OFF_CST   = OFF_IV + B * K * M; // [B*K]   -0.5*sum_m log(2*pi*var)
constexpr int OFF_LL    = OFF_CST + B * K;    // [B]     sum(mask*ll)
constexpr int WS_FLOATS = OFF_LL + B;

__device__ __forceinline__ float wave_reduce(float v) {
    #pragma unroll
    for (int off = 32; off > 0; off >>= 1) v += __shfl_down(v, off, 64);
    return v;
}

__global__ __launch_bounds__(THREADS) void pass1_kernel(
    const float* __restrict__ pred, const float* __restrict__ xin,
    const int* __restrict__ heart, float* __restrict__ ws) {
    const int b  = blockIdx.x / BLOCKS_PER_B;
    const int cb = blockIdx.x % BLOCKS_PER_B;
    const int p0 = (cb * THREADS + threadIdx.x) * 4;

    const int4 h4 = *(const int4*)(heart + b * NPIX + p0);
    float mk[4];
    mk[0] = (h4.x == 1) ? 1.0f : 0.0f;
    mk[1] = (h4.y == 1) ? 1.0f : 0.0f;
    mk[2] = (h4.z == 1) ? 1.0f : 0.0f;
    mk[3] = (h4.w == 1) ? 1.0f : 0.0f;

    float xv[M][4];
    #pragma unroll
    for (int m = 0; m < M; ++m) {
        float4 t = *(const float4*)(xin + (b * M + m) * NPIX + p0);
        xv[m][0] = t.x; xv[m][1] = t.y; xv[m][2] = t.z; xv[m][3] = t.w;
    }

    float nacc = mk[0] + mk[1] + mk[2] + mk[3];
    float Wk[K];
    float Pa[K][M];
    float Qa[K][M];

    #pragma unroll
    for (int k = 0; k < K; ++k) {
        float4 pr = *(const float4*)(pred + (b * K + k) * NPIX + p0);
        float pm[4];
        pm[0] = pr.x * mk[0]; pm[1] = pr.y * mk[1];
        pm[2] = pr.z * mk[2]; pm[3] = pr.w * mk[3];
        Wk[k] = (pm[0] + pm[1]) + (pm[2] + pm[3]);
        #pragma unroll
        for (int m = 0; m < M; ++m) {
            float p = 0.0f, q = 0.0f;
            #pragma unroll
            for (int j = 0; j < 4; ++j) {
                float px = pm[j] * xv[m][j];
                p += px;
                q += px * xv[m][j];
            }
            Pa[k][m] = p;
            Qa[k][m] = q;
        }
    }

    // pack and wave-reduce 29 values
    float vals[1 + K + 2 * K * M];
    vals[0] = nacc;
    #pragma unroll
    for (int k = 0; k < K; ++k) vals[1 + k] = Wk[k];
    #pragma unroll
    for (int k = 0; k < K; ++k)
        #pragma unroll
        for (int m = 0; m < M; ++m) {
            vals[1 + K + k * M + m]         = Pa[k][m];
            vals[1 + K + K * M + k * M + m] = Qa[k][m];
        }

    #pragma unroll
    for (int i = 0; i < 1 + K + 2 * K * M; ++i) vals[i] = wave_reduce(vals[i]);

    if ((threadIdx.x & 63) == 0) {
        atomicAdd(&ws[OFF_N + b], vals[0]);
        #pragma unroll
        for (int k = 0; k < K; ++k) atomicAdd(&ws[OFF_W + b * K + k], vals[1 + k]);
        #pragma unroll
        for (int k = 0; k < K; ++k)
            #pragma unroll
            for (int m = 0; m < M; ++m) {
                atomicAdd(&ws[OFF_P + (b * K + k) * M + m], vals[1 + K + k * M + m]);
                atomicAdd(&ws[OFF_Q + (b * K + k) * M + m], vals[1 + K + K * M + k * M + m]);
            }
    }
}

__global__ __launch_bounds__(128) void params_kernel(float* __restrict__ ws) {
    const int t = threadIdx.x;
    if (t >= B * K) return;
    const int b = t / K;
    const float n = ws[OFF_N + b];
    const float W = ws[OFF_W + t];
    const float s = W + EPSF;
    ws[OFF_ALPHA + t] = W / n;
    float cst = 0.0f;
    #pragma unroll
    for (int m = 0; m < M; ++m) {
        const float Pv = ws[OFF_P + t * M + m];
        const float Qv = ws[OFF_Q + t * M + m];
        const float mu = Pv / s;
        const float var = (Qv - 2.0f * mu * Pv + mu * mu * W) / s + EPSF;
        ws[OFF_MU + t * M + m] = mu;
        ws[OFF_IV + t * M + m] = 0.5f / var;
        cst -= 0.5f * logf(6.2831853071795864f * var);
    }
    ws[OFF_CST + t] = cst;
}

__global__ __launch_bounds__(THREADS) void pass2_kernel(
    const float* __restrict__ xin, const int* __restrict__ heart,
    float* __restrict__ ws) {
    const int b  = blockIdx.x / BLOCKS_PER_B;
    const int cb = blockIdx.x % BLOCKS_PER_B;
    const int p0 = (cb * THREADS + threadIdx.x) * 4;

    // per-b params (uniform across block -> scalar-cached loads)
    float alpha[K], cst[K], mu[K][M], iv[K][M];
    #pragma unroll
    for (int k = 0; k < K; ++k) {
        alpha[k] = ws[OFF_ALPHA + b * K + k];
        cst[k]   = ws[OFF_CST + b * K + k];
        #pragma unroll
        for (int m = 0; m < M; ++m) {
            mu[k][m] = ws[OFF_MU + (b * K + k) * M + m];
            iv[k][m] = ws[OFF_IV + (b * K + k) * M + m];
        }
    }

    const int4 h4 = *(const int4*)(heart + b * NPIX + p0);
    int hv[4] = {h4.x, h4.y, h4.z, h4.w};

    float xv[M][4];
    #pragma unroll
    for (int m = 0; m < M; ++m) {
        float4 t = *(const float4*)(xin + (b * M + m) * NPIX + p0);
        xv[m][0] = t.x; xv[m][1] = t.y; xv[m][2] = t.z; xv[m][3] = t.w;
    }

    float acc = 0.0f;  // sum of mask * ll
    #pragma unroll
    for (int j = 0; j < 4; ++j) {
        float mix = EPSF;
        #pragma unroll
        for (int k = 0; k < K; ++k) {
            float lp = cst[k];
            #pragma unroll
            for (int m = 0; m < M; ++m) {
                float d = xv[m][j] - mu[k][m];
                lp -= d * d * iv[k][m];
            }
            mix += alpha[k] * __expf(lp);
        }
        float mask = (hv[j] == 1) ? 1.0f : 0.0f;
        acc += mask * __logf(mix);
    }

    acc = wave_reduce(acc);
    if ((threadIdx.x & 63) == 0) atomicAdd(&ws[OFF_LL + b], acc);
}

__global__ void final_kernel(const float* __restrict__ ws, float* __restrict__ out) {
    if (threadIdx.x == 0 && blockIdx.x == 0) {
        float r = 0.0f;
        for (int b = 0; b < B; ++b) r += -ws[OFF_LL + b] / ws[OFF_N + b];
        out[0] = r / (float)B;
    }
}

extern "C" void kernel_launch(void* const* d_in, const int* in_sizes, int n_in,
                              void* d_out, int out_size, void* d_ws, size_t ws_size,
                              hipStream_t stream) {
    const float* pred  = (const float*)d_in[0];
    const float* xin   = (const float*)d_in[1];
    const int*   heart = (const int*)d_in[2];
    float* out = (float*)d_out;
    float* ws  = (float*)d_ws;

    hipMemsetAsync(d_ws, 0, WS_FLOATS * sizeof(float), stream);
    pass1_kernel<<<B * BLOCKS_PER_B, THREADS, 0, stream>>>(pred, xin, heart, ws);
    params_kernel<<<1, 128, 0, stream>>>(ws);
    pass2_kernel<<<B * BLOCKS_PER_B, THREADS, 0, stream>>>(xin, heart, ws);
    final_kernel<<<1, 64, 0, stream>>>(ws, out);
}

// Round 2
// 113.230 us; speedup vs baseline: 2.8530x; 2.8530x over previous
//
#include <hip/hip_runtime.h>

#define EPSF 1e-10f

constexpr int B = 32, K = 4, M = 3;
constexpr int NPIX = 256 * 256;
constexpr int BLOCKS_PER_B = 8;    // 8 blocks per b -> 256 blocks total (1/CU)
constexpr int THREADS = 256;
constexpr int WAVES = THREADS / 64;
constexpr int CHUNKS = NPIX / (BLOCKS_PER_B * THREADS * 4);  // 8 iters/thread
constexpr int NVALS = 1 + K + 2 * K * M;  // 29 reduced values in pass1

// workspace float layout
constexpr int OFF_N     = 0;                  // [B]     sum(mask)
constexpr int OFF_W     = OFF_N + B;          // [B*K]   sum(mask*pred)
constexpr int OFF_P     = OFF_W + B * K;      // [B*K*M] sum(mask*pred*x)
constexpr int OFF_Q     = OFF_P + B * K * M;  // [B*K*M] sum(mask*pred*x^2)
constexpr int OFF_ALPHA = OFF_Q + B * K * M;  // [B*K]
constexpr int OFF_MU    = OFF_ALPHA + B * K;  // [B*K*M]
constexpr int OFF_IV    = OFF_MU + B * K * M; // [B*K*M] 1/(2*var)
constexpr int OFF_CST   = OFF_IV + B * K * M; // [B*K]   -0.5*sum_m log(2*pi*var)
constexpr int OFF_LL    = OFF_CST + B * K;    // [B]     sum(mask*ll)
constexpr int WS_FLOATS = OFF_LL + B;

__device__ __forceinline__ float wave_reduce(float v) {
    #pragma unroll
    for (int off = 32; off > 0; off >>= 1) v += __shfl_down(v, off, 64);
    return v;
}

__global__ __launch_bounds__(THREADS) void pass1_kernel(
    const float* __restrict__ pred, const float* __restrict__ xin,
    const int* __restrict__ heart, float* __restrict__ ws) {
    const int b  = blockIdx.x / BLOCKS_PER_B;
    const int cb = blockIdx.x % BLOCKS_PER_B;

    float nacc = 0.0f;
    float Wk[K] = {};
    float Pa[K][M] = {};
    float Qa[K][M] = {};

    for (int it = 0; it < CHUNKS; ++it) {
        const int p0 = (((cb * CHUNKS + it) * THREADS) + threadIdx.x) * 4;

        const int4 h4 = *(const int4*)(heart + b * NPIX + p0);
        float mk[4];
        mk[0] = (h4.x == 1) ? 1.0f : 0.0f;
        mk[1] = (h4.y == 1) ? 1.0f : 0.0f;
        mk[2] = (h4.z == 1) ? 1.0f : 0.0f;
        mk[3] = (h4.w == 1) ? 1.0f : 0.0f;
        nacc += (mk[0] + mk[1]) + (mk[2] + mk[3]);

        float xv[M][4];
        #pragma unroll
        for (int m = 0; m < M; ++m) {
            float4 t = *(const float4*)(xin + (b * M + m) * NPIX + p0);
            xv[m][0] = t.x; xv[m][1] = t.y; xv[m][2] = t.z; xv[m][3] = t.w;
        }

        #pragma unroll
        for (int k = 0; k < K; ++k) {
            float4 pr = *(const float4*)(pred + (b * K + k) * NPIX + p0);
            float pm[4];
            pm[0] = pr.x * mk[0]; pm[1] = pr.y * mk[1];
            pm[2] = pr.z * mk[2]; pm[3] = pr.w * mk[3];
            Wk[k] += (pm[0] + pm[1]) + (pm[2] + pm[3]);
            #pragma unroll
            for (int m = 0; m < M; ++m) {
                #pragma unroll
                for (int j = 0; j < 4; ++j) {
                    float px = pm[j] * xv[m][j];
                    Pa[k][m] += px;
                    Qa[k][m] += px * xv[m][j];
                }
            }
        }
    }

    // pack 29 values
    float vals[NVALS];
    vals[0] = nacc;
    #pragma unroll
    for (int k = 0; k < K; ++k) vals[1 + k] = Wk[k];
    #pragma unroll
    for (int k = 0; k < K; ++k)
        #pragma unroll
        for (int m = 0; m < M; ++m) {
            vals[1 + K + k * M + m]         = Pa[k][m];
            vals[1 + K + K * M + k * M + m] = Qa[k][m];
        }

    // wave reduce -> LDS -> cross-wave reduce -> ONE atomic per value per block
    __shared__ float red[WAVES * NVALS];
    #pragma unroll
    for (int i = 0; i < NVALS; ++i) vals[i] = wave_reduce(vals[i]);
    const int wave = threadIdx.x >> 6;
    if ((threadIdx.x & 63) == 0) {
        #pragma unroll
        for (int i = 0; i < NVALS; ++i) red[wave * NVALS + i] = vals[i];
    }
    __syncthreads();
    // 29 threads each own one value: sum 4 waves, single atomic
    const int i = threadIdx.x;
    if (i < NVALS) {
        float s = red[i];
        #pragma unroll
        for (int w = 1; w < WAVES; ++w) s += red[w * NVALS + i];
        int dst;
        if (i == 0)            dst = OFF_N + b;
        else if (i < 1 + K)    dst = OFF_W + b * K + (i - 1);
        else if (i < 1 + K + K * M) dst = OFF_P + b * K * M + (i - 1 - K);
        else                   dst = OFF_Q + b * K * M + (i - 1 - K - K * M);
        atomicAdd(&ws[dst], s);
    }
}

__global__ __launch_bounds__(128) void params_kernel(float* __restrict__ ws) {
    const int t = threadIdx.x;
    if (t >= B * K) return;
    const int b = t / K;
    const float n = ws[OFF_N + b];
    const float W = ws[OFF_W + t];
    const float s = W + EPSF;
    ws[OFF_ALPHA + t] = W / n;
    float cst = 0.0f;
    #pragma unroll
    for (int m = 0; m < M; ++m) {
        const float Pv = ws[OFF_P + t * M + m];
        const float Qv = ws[OFF_Q + t * M + m];
        const float mu = Pv / s;
        const float var = (Qv - 2.0f * mu * Pv + mu * mu * W) / s + EPSF;
        ws[OFF_MU + t * M + m] = mu;
        ws[OFF_IV + t * M + m] = 0.5f / var;
        cst -= 0.5f * logf(6.2831853071795864f * var);
    }
    ws[OFF_CST + t] = cst;
}

__global__ __launch_bounds__(THREADS) void pass2_kernel(
    const float* __restrict__ xin, const int* __restrict__ heart,
    float* __restrict__ ws) {
    const int b  = blockIdx.x / BLOCKS_PER_B;
    const int cb = blockIdx.x % BLOCKS_PER_B;

    float alpha[K], cst[K], mu[K][M], iv[K][M];
    #pragma unroll
    for (int k = 0; k < K; ++k) {
        alpha[k] = ws[OFF_ALPHA + b * K + k];
        cst[k]   = ws[OFF_CST + b * K + k];
        #pragma unroll
        for (int m = 0; m < M; ++m) {
            mu[k][m] = ws[OFF_MU + (b * K + k) * M + m];
            iv[k][m] = ws[OFF_IV + (b * K + k) * M + m];
        }
    }

    float acc = 0.0f;  // sum of mask * ll
    for (int it = 0; it < CHUNKS; ++it) {
        const int p0 = (((cb * CHUNKS + it) * THREADS) + threadIdx.x) * 4;

        const int4 h4 = *(const int4*)(heart + b * NPIX + p0);
        int hv[4] = {h4.x, h4.y, h4.z, h4.w};

        float xv[M][4];
        #pragma unroll
        for (int m = 0; m < M; ++m) {
            float4 t = *(const float4*)(xin + (b * M + m) * NPIX + p0);
            xv[m][0] = t.x; xv[m][1] = t.y; xv[m][2] = t.z; xv[m][3] = t.w;
        }

        #pragma unroll
        for (int j = 0; j < 4; ++j) {
            float mix = EPSF;
            #pragma unroll
            for (int k = 0; k < K; ++k) {
                float lp = cst[k];
                #pragma unroll
                for (int m = 0; m < M; ++m) {
                    float d = xv[m][j] - mu[k][m];
                    lp -= d * d * iv[k][m];
                }
                mix += alpha[k] * __expf(lp);
            }
            float mask = (hv[j] == 1) ? 1.0f : 0.0f;
            acc += mask * __logf(mix);
        }
    }

    __shared__ float red[WAVES];
    acc = wave_reduce(acc);
    const int wave = threadIdx.x >> 6;
    if ((threadIdx.x & 63) == 0) red[wave] = acc;
    __syncthreads();
    if (threadIdx.x == 0) {
        float s = red[0];
        #pragma unroll
        for (int w = 1; w < WAVES; ++w) s += red[w];
        atomicAdd(&ws[OFF_LL + b], s);
    }
}

__global__ void final_kernel(const float* __restrict__ ws, float* __restrict__ out) {
    if (threadIdx.x == 0 && blockIdx.x == 0) {
        float r = 0.0f;
        for (int b = 0; b < B; ++b) r += -ws[OFF_LL + b] / ws[OFF_N + b];
        out[0] = r / (float)B;
    }
}

extern "C" void kernel_launch(void* const* d_in, const int* in_sizes, int n_in,
                              void* d_out, int out_size, void* d_ws, size_t ws_size,
                              hipStream_t stream) {
    const float* pred  = (const float*)d_in[0];
    const float* xin   = (const float*)d_in[1];
    const int*   heart = (const int*)d_in[2];
    float* out = (float*)d_out;
    float* ws  = (float*)d_ws;

    hipMemsetAsync(d_ws, 0, WS_FLOATS * sizeof(float), stream);
    pass1_kernel<<<B * BLOCKS_PER_B, THREADS, 0, stream>>>(pred, xin, heart, ws);
    params_kernel<<<1, 128, 0, stream>>>(ws);
    pass2_kernel<<<B * BLOCKS_PER_B, THREADS, 0, stream>>>(xin, heart, ws);
    final_kernel<<<1, 64, 0, stream>>>(ws, out);
}